// Round 2
// baseline (199.595 us; speedup 1.0000x reference)
//
#include <hip/hip_runtime.h>

// Volume rendering (NeRF-style fancy_integration), f32 in/out.
// B=4, R=32768, S=64  -> 131072 rays, 64 samples each.
// One 64-lane wave per ray; lane i handles sample i.
//
// Round 2: all cross-lane traffic moved from ds_bpermute (__shfl_*, LDS pipe,
// ~35cy latency + lgkmcnt stalls) to DPP (pure VALU, ~4cy dep latency).
// Round 1 counters showed VALUBusy 34% / HBM 22% / occupancy 69% -> latency
// bound on the serial bpermute chains, so shift work onto the idle VALU pipe.

#define NSAMP 64
#define EPS_W 1e-10f
#define DELTA_INF_V 1e10f

// DPP ctrl encodings (gfx9/CDNA classic DPP)
#define DPP_ROW_SHR(n)  (0x110 | (n))
#define DPP_ROW_BCAST15 0x142
#define DPP_ROW_BCAST31 0x143
#define DPP_WAVE_SHL1   0x130   // lane i <- lane i+1 (data moves to lower lanes)
#define DPP_WAVE_SHR1   0x138   // lane i <- lane i-1 (data moves to higher lanes)

// update_dpp: lanes with invalid/masked source get `old`.
template <int CTRL, int RM, int BM>
__device__ __forceinline__ float dpp_mov(float x, float old) {
    return __builtin_bit_cast(float,
        __builtin_amdgcn_update_dpp(
            __builtin_bit_cast(int, old), __builtin_bit_cast(int, x),
            CTRL, RM, BM, false));
}

// Inclusive multiply-scan across 64 lanes. Identity 1.0 via `old`.
__device__ __forceinline__ float scan_mul64(float p) {
    p *= dpp_mov<DPP_ROW_SHR(1), 0xf, 0xf>(p, 1.0f);
    p *= dpp_mov<DPP_ROW_SHR(2), 0xf, 0xf>(p, 1.0f);
    p *= dpp_mov<DPP_ROW_SHR(4), 0xf, 0xf>(p, 1.0f);
    p *= dpp_mov<DPP_ROW_SHR(8), 0xf, 0xf>(p, 1.0f);
    p *= dpp_mov<DPP_ROW_BCAST15, 0xa, 0xf>(p, 1.0f);  // rows 1,3 *= lane15/47
    p *= dpp_mov<DPP_ROW_BCAST31, 0xc, 0xf>(p, 1.0f);  // rows 2,3 *= lane31
    return p;  // lane i = prod(lanes 0..i)
}

// Inclusive add-scan; lane 63 ends with the full 64-lane sum.
__device__ __forceinline__ float scan_add64(float x) {
    x += dpp_mov<DPP_ROW_SHR(1), 0xf, 0xf>(x, 0.0f);
    x += dpp_mov<DPP_ROW_SHR(2), 0xf, 0xf>(x, 0.0f);
    x += dpp_mov<DPP_ROW_SHR(4), 0xf, 0xf>(x, 0.0f);
    x += dpp_mov<DPP_ROW_SHR(8), 0xf, 0xf>(x, 0.0f);
    x += dpp_mov<DPP_ROW_BCAST15, 0xa, 0xf>(x, 0.0f);
    x += dpp_mov<DPP_ROW_BCAST31, 0xc, 0xf>(x, 0.0f);
    return x;
}

__global__ __launch_bounds__(256) void volrend_kernel(
    const float* __restrict__ rgb,      // [n_rays, 64, 3]
    const float* __restrict__ sigma,    // [n_rays, 64]
    const float* __restrict__ z_vals,   // [n_rays, 64]
    float* __restrict__ rgb_out,        // [n_rays, 3]
    float* __restrict__ depth_out,      // [n_rays]
    float* __restrict__ weights_out,    // [n_rays, 64]
    int n_rays)
{
    const int lane = threadIdx.x & 63;
    const int wave = threadIdx.x >> 6;
    const int ray  = blockIdx.x * (blockDim.x >> 6) + wave;
    if (ray >= n_rays) return;

    const long long base = (long long)ray * NSAMP + lane;

    // Coalesced per-lane loads
    const float sg = sigma[base];
    const float z  = z_vals[base];
    const float* rp = rgb + base * 3;
    const float cr = rp[0];
    const float cg = rp[1];
    const float cb = rp[2];

    // delta_i = z_{i+1} - z_i ; last = 1e10
    const float z_next = dpp_mov<DPP_WAVE_SHL1, 0xf, 0xf>(z, 0.0f);
    const float delta  = (lane == NSAMP - 1) ? DELTA_INF_V : (z_next - z);

    // alpha = 1 - exp(-delta * relu(sigma))
    const float alpha = 1.0f - __expf(-delta * fmaxf(sg, 0.0f));

    // exclusive prefix product of (1 - alpha + eps): inclusive scan, then
    // shift up one lane (wave_shr:1); lane 0 gets identity 1.0 via `old`.
    const float p = scan_mul64(1.0f - alpha + EPS_W);
    const float T = dpp_mov<DPP_WAVE_SHR1, 0xf, 0xf>(p, 1.0f);

    const float w = alpha * T;

    // weights output (coalesced)
    weights_out[base] = w;

    // full-wave sums land in lane 63
    const float sr = scan_add64(w * cr);
    const float sg2 = scan_add64(w * cg);
    const float sb = scan_add64(w * cb);
    const float sd = scan_add64(w * z);

    if (lane == NSAMP - 1) {
        rgb_out[(long long)ray * 3 + 0] = sr;
        rgb_out[(long long)ray * 3 + 1] = sg2;
        rgb_out[(long long)ray * 3 + 2] = sb;
        depth_out[ray] = sd;
    }
}

extern "C" void kernel_launch(void* const* d_in, const int* in_sizes, int n_in,
                              void* d_out, int out_size, void* d_ws, size_t ws_size,
                              hipStream_t stream) {
    const float* rgb    = (const float*)d_in[0];   // [B,R,S,3]
    const float* sigma  = (const float*)d_in[1];   // [B,R,S,1]
    const float* z_vals = (const float*)d_in[2];   // [B,R,S,1]

    const int n_rays = in_sizes[1] / NSAMP;        // B*R = 131072

    float* out         = (float*)d_out;
    float* rgb_out     = out;                              // n_rays*3
    float* depth_out   = out + (long long)n_rays * 3;      // n_rays
    float* weights_out = out + (long long)n_rays * 4;      // n_rays*64

    const int block = 256;                 // 4 waves = 4 rays per block
    const int rays_per_block = block / 64;
    const int grid = (n_rays + rays_per_block - 1) / rays_per_block;

    volrend_kernel<<<grid, block, 0, stream>>>(
        rgb, sigma, z_vals, rgb_out, depth_out, weights_out, n_rays);
}